// Round 1
// baseline (451.242 us; speedup 1.0000x reference)
//
#include <hip/hip_runtime.h>
#include <stdint.h>

// Problem dims (fixed)
// B=2, S=2048, D=1024, H=16, DH=64, tokens T=4096

typedef __attribute__((ext_vector_type(8))) short short8;
typedef __attribute__((ext_vector_type(4))) float f32x4;

__device__ __forceinline__ unsigned short f2b(float f) {
  union { float f; unsigned u; } v; v.f = f;
  unsigned u = v.u;
  return (unsigned short)((u + 0x7fffu + ((u >> 16) & 1u)) >> 16);
}

// ---------------- cast hidden_states fp32 -> bf16 ----------------
__global__ void k_cast_hs(const float* __restrict__ x, unsigned short* __restrict__ y, int n4) {
  int i = blockIdx.x * blockDim.x + threadIdx.x;
  if (i < n4) {
    float4 v = ((const float4*)x)[i];
    ushort4 o;
    o.x = f2b(v.x); o.y = f2b(v.y); o.z = f2b(v.z); o.w = f2b(v.w);
    ((ushort4*)y)[i] = o;
  }
}

// ---------------- transpose+cast the four weight matrices ----------------
// WT[n][k] = W[k][n], bf16 out. Block (32,8), 32x32 tile, z picks matrix.
__global__ void k_transpose_cast(const float* __restrict__ Wq, const float* __restrict__ Wk,
                                 const float* __restrict__ Wv, const float* __restrict__ Wo,
                                 unsigned short* __restrict__ Tq, unsigned short* __restrict__ Tk,
                                 unsigned short* __restrict__ Tv, unsigned short* __restrict__ To) {
  __shared__ float tile[32][33];
  const float* W; unsigned short* T;
  switch (blockIdx.z) {
    case 0: W = Wq; T = Tq; break;
    case 1: W = Wk; T = Tk; break;
    case 2: W = Wv; T = Tv; break;
    default: W = Wo; T = To; break;
  }
  int n0 = blockIdx.x * 32, k0 = blockIdx.y * 32;
  int tx = threadIdx.x, ty = threadIdx.y;
#pragma unroll
  for (int j = 0; j < 4; ++j)
    tile[ty + j * 8][tx] = W[(size_t)(k0 + ty + j * 8) * 1024 + n0 + tx];
  __syncthreads();
#pragma unroll
  for (int j = 0; j < 4; ++j)
    T[(size_t)(n0 + ty + j * 8) * 1024 + k0 + tx] = f2b(tile[tx][ty + j * 8]);
}

// ---------------- m97-style 128x128 bf16 MFMA GEMM, C = A @ Bt^T ----------------
// MODE 0: out bf16 [B,H,S,DH], rows=tokens, cols=D, +bias[col]     (Q, K)
// MODE 1: out bf16 [B,H,DH,S], rows=D (dims), cols=tokens, +bias[row]  (V transposed)
// MODE 2: out fp32 h[row*1024+col] = acc + bias[col] + resid[row*1024+col]  (out proj)
template <int MODE>
__global__ __launch_bounds__(256) void k_gemm(const unsigned short* __restrict__ A,
                                              const unsigned short* __restrict__ Bt, int Kd,
                                              const float* __restrict__ bias,
                                              const float* __restrict__ resid,
                                              void* __restrict__ outp) {
  __shared__ __align__(16) unsigned short Asm[128 * 32];
  __shared__ __align__(16) unsigned short Bsm[128 * 32];
  const int t = threadIdx.x, w = t >> 6, l = t & 63;
  const int m0 = blockIdx.y * 128, n0 = blockIdx.x * 128;
  const int wr = w >> 1, wc = w & 1;
  const int lr = l & 15, lg = l >> 4;

  f32x4 acc[4][4];
#pragma unroll
  for (int mi = 0; mi < 4; ++mi)
#pragma unroll
    for (int ni = 0; ni < 4; ++ni) acc[mi][ni] = (f32x4){0.f, 0.f, 0.f, 0.f};

  const int kcol = (l & 3) * 8;
  for (int kt = 0; kt < Kd / 32; ++kt) {
    const int k0 = kt * 32;
#pragma unroll
    for (int i = 0; i < 2; ++i) {
      int ra = (i * 4 + w) * 16 + (l >> 2);
      const unsigned short* ga = A + (size_t)(m0 + ra) * Kd + k0 + kcol;
      __builtin_amdgcn_global_load_lds((const __attribute__((address_space(1))) void*)ga,
                                       (__attribute__((address_space(3))) void*)((char*)Asm + (i * 4 + w) * 1024),
                                       16, 0, 0);
      const unsigned short* gb = Bt + (size_t)(n0 + ra) * Kd + k0 + kcol;
      __builtin_amdgcn_global_load_lds((const __attribute__((address_space(1))) void*)gb,
                                       (__attribute__((address_space(3))) void*)((char*)Bsm + (i * 4 + w) * 1024),
                                       16, 0, 0);
    }
    __syncthreads();
    short8 af[4], bfv[4];
#pragma unroll
    for (int mi = 0; mi < 4; ++mi)
      af[mi] = *(const short8*)&Asm[(wr * 64 + mi * 16 + lr) * 32 + lg * 8];
#pragma unroll
    for (int ni = 0; ni < 4; ++ni)
      bfv[ni] = *(const short8*)&Bsm[(wc * 64 + ni * 16 + lr) * 32 + lg * 8];
#pragma unroll
    for (int mi = 0; mi < 4; ++mi)
#pragma unroll
      for (int ni = 0; ni < 4; ++ni)
        acc[mi][ni] = __builtin_amdgcn_mfma_f32_16x16x32_bf16(af[mi], bfv[ni], acc[mi][ni], 0, 0, 0);
    __syncthreads();
  }

#pragma unroll
  for (int mi = 0; mi < 4; ++mi) {
#pragma unroll
    for (int ni = 0; ni < 4; ++ni) {
#pragma unroll
      for (int r = 0; r < 4; ++r) {
        int row = m0 + wr * 64 + mi * 16 + lg * 4 + r;
        int col = n0 + wc * 64 + ni * 16 + lr;
        float v = acc[mi][ni][r];
        if constexpr (MODE == 0) {
          v += bias[col];
          int b = row >> 11, s = row & 2047, h = col >> 6, dh = col & 63;
          ((unsigned short*)outp)[((size_t)((b * 16 + h) * 2048 + s)) * 64 + dh] = f2b(v);
        } else if constexpr (MODE == 1) {
          v += bias[row];
          int h = row >> 6, dh = row & 63, b = col >> 11, s = col & 2047;
          ((unsigned short*)outp)[((size_t)((b * 16 + h) * 64 + dh)) * 2048 + s] = f2b(v);
        } else {
          v += bias[col] + resid[(size_t)row * 1024 + col];
          ((float*)outp)[(size_t)row * 1024 + col] = v;
        }
      }
    }
  }
}

// ---------------- fused attention: scores + softmax + probs write + PV ----------------
// grid (S/16, H, B), block 256 (4 waves). Wave w owns score cols [w*512, w*512+512).
__global__ __launch_bounds__(256) void k_attn(const unsigned short* __restrict__ Q,
                                              const unsigned short* __restrict__ K,
                                              const unsigned short* __restrict__ VT,
                                              const float* __restrict__ mask,
                                              float* __restrict__ probs,
                                              unsigned short* __restrict__ ctx) {
  __shared__ float smax[4][16];
  __shared__ float ssum[4][16];
  __shared__ __align__(16) unsigned short pbuf[4][16][264];  // per-wave P chunk (16 rows x 256 k)
  __shared__ float redbuf[4][16][64];

  const int t = threadIdx.x, w = t >> 6, l = t & 63;
  const int qb = blockIdx.x, h = blockIdx.y, b = blockIdx.z;
  const int q0 = qb * 16;
  const int lr = l & 15, lg = l >> 4;
  const size_t head = ((size_t)(b * 16 + h)) * 2048 * 64;
  const unsigned short* Qh = Q + head + (size_t)q0 * 64;
  const unsigned short* Kh = K + head;
  const unsigned short* VTh = VT + head;

  short8 aq0 = *(const short8*)(Qh + lr * 64 + lg * 8);
  short8 aq1 = *(const short8*)(Qh + lr * 64 + 32 + lg * 8);

  f32x4 sc[32];
  const float scale = 0.125f;
#pragma unroll
  for (int ni = 0; ni < 32; ++ni) {
    int col = w * 512 + ni * 16 + lr;
    short8 bk0 = *(const short8*)(Kh + (size_t)col * 64 + lg * 8);
    short8 bk1 = *(const short8*)(Kh + (size_t)col * 64 + 32 + lg * 8);
    f32x4 c = (f32x4){0.f, 0.f, 0.f, 0.f};
    c = __builtin_amdgcn_mfma_f32_16x16x32_bf16(aq0, bk0, c, 0, 0, 0);
    c = __builtin_amdgcn_mfma_f32_16x16x32_bf16(aq1, bk1, c, 0, 0, 0);
    float mval = mask[b * 2048 + col];
#pragma unroll
    for (int r = 0; r < 4; ++r) sc[ni][r] = c[r] * scale + mval;
  }

  // ---- softmax over 2048 cols per row ----
  float vmax[4] = {-1e30f, -1e30f, -1e30f, -1e30f};
#pragma unroll
  for (int ni = 0; ni < 32; ++ni)
#pragma unroll
    for (int r = 0; r < 4; ++r) vmax[r] = fmaxf(vmax[r], sc[ni][r]);
#pragma unroll
  for (int off = 8; off >= 1; off >>= 1)
#pragma unroll
    for (int r = 0; r < 4; ++r) vmax[r] = fmaxf(vmax[r], __shfl_xor(vmax[r], off));
  if (lr == 0) {
#pragma unroll
    for (int r = 0; r < 4; ++r) smax[w][lg * 4 + r] = vmax[r];
  }
  __syncthreads();
  float m[4];
#pragma unroll
  for (int r = 0; r < 4; ++r) {
    int row = lg * 4 + r;
    m[r] = fmaxf(fmaxf(smax[0][row], smax[1][row]), fmaxf(smax[2][row], smax[3][row]));
  }
  float vsum[4] = {0.f, 0.f, 0.f, 0.f};
#pragma unroll
  for (int ni = 0; ni < 32; ++ni)
#pragma unroll
    for (int r = 0; r < 4; ++r) {
      float p = __expf(sc[ni][r] - m[r]);
      sc[ni][r] = p;
      vsum[r] += p;
    }
#pragma unroll
  for (int off = 8; off >= 1; off >>= 1)
#pragma unroll
    for (int r = 0; r < 4; ++r) vsum[r] += __shfl_xor(vsum[r], off);
  if (lr == 0) {
#pragma unroll
    for (int r = 0; r < 4; ++r) ssum[w][lg * 4 + r] = vsum[r];
  }
  __syncthreads();
  float rinv[4];
#pragma unroll
  for (int r = 0; r < 4; ++r) {
    int row = lg * 4 + r;
    rinv[r] = 1.f / (ssum[0][row] + ssum[1][row] + ssum[2][row] + ssum[3][row]);
  }

  // normalize + write probs fp32
#pragma unroll
  for (int ni = 0; ni < 32; ++ni) {
#pragma unroll
    for (int r = 0; r < 4; ++r) {
      sc[ni][r] *= rinv[r];
      int row = q0 + lg * 4 + r;
      int col = w * 512 + ni * 16 + lr;
      probs[((size_t)((b * 16 + h) * 2048 + row)) * 2048 + col] = sc[ni][r];
    }
  }

  // ---- PV: ctx[16 x 64], K-dim split across waves (each wave its 512 cols) ----
  f32x4 cacc[4];
#pragma unroll
  for (int n = 0; n < 4; ++n) cacc[n] = (f32x4){0.f, 0.f, 0.f, 0.f};

#pragma unroll
  for (int chunk = 0; chunk < 2; ++chunk) {
    // write P chunk (bf16) to this wave's LDS slot, transposable layout
#pragma unroll
    for (int ni2 = 0; ni2 < 16; ++ni2) {
      int ni = chunk * 16 + ni2;
#pragma unroll
      for (int r = 0; r < 4; ++r)
        pbuf[w][lg * 4 + r][ni2 * 16 + lr] = f2b(sc[ni][r]);
    }
    __syncthreads();
#pragma unroll
    for (int kc = 0; kc < 8; ++kc) {
      short8 pa = *(const short8*)&pbuf[w][lr][kc * 32 + lg * 8];
      size_t kg = (size_t)w * 512 + chunk * 256 + kc * 32;
#pragma unroll
      for (int n = 0; n < 4; ++n) {
        short8 bv = *(const short8*)(VTh + (size_t)(n * 16 + lr) * 2048 + kg + lg * 8);
        cacc[n] = __builtin_amdgcn_mfma_f32_16x16x32_bf16(pa, bv, cacc[n], 0, 0, 0);
      }
    }
    __syncthreads();
  }

  // cross-wave reduce of ctx partials
#pragma unroll
  for (int n = 0; n < 4; ++n)
#pragma unroll
    for (int r = 0; r < 4; ++r)
      redbuf[w][lg * 4 + r][n * 16 + lr] = cacc[n][r];
  __syncthreads();

  {
    int row = t >> 4;          // 0..15
    int c0 = (t & 15) * 4;     // 0..60
    float v0 = redbuf[0][row][c0] + redbuf[1][row][c0] + redbuf[2][row][c0] + redbuf[3][row][c0];
    float v1 = redbuf[0][row][c0 + 1] + redbuf[1][row][c0 + 1] + redbuf[2][row][c0 + 1] + redbuf[3][row][c0 + 1];
    float v2 = redbuf[0][row][c0 + 2] + redbuf[1][row][c0 + 2] + redbuf[2][row][c0 + 2] + redbuf[3][row][c0 + 2];
    float v3 = redbuf[0][row][c0 + 3] + redbuf[1][row][c0 + 3] + redbuf[2][row][c0 + 3] + redbuf[3][row][c0 + 3];
    ushort4 o;
    o.x = f2b(v0); o.y = f2b(v1); o.z = f2b(v2); o.w = f2b(v3);
    *(ushort4*)(ctx + ((size_t)(b * 2048 + q0 + row)) * 1024 + h * 64 + c0) = o;
  }
}

// ---------------- LayerNorm over D=1024 per token ----------------
__global__ __launch_bounds__(256) void k_ln(const float* __restrict__ hbuf, const float* __restrict__ g,
                                            const float* __restrict__ be, float* __restrict__ out) {
  __shared__ float psum[4];
  __shared__ float psq[4];
  int tok = blockIdx.x;
  int t = threadIdx.x, w = t >> 6;
  float4 v = ((const float4*)(hbuf + (size_t)tok * 1024))[t];
  float s = v.x + v.y + v.z + v.w;
  float q = v.x * v.x + v.y * v.y + v.z * v.z + v.w * v.w;
#pragma unroll
  for (int off = 32; off >= 1; off >>= 1) {
    s += __shfl_xor(s, off);
    q += __shfl_xor(q, off);
  }
  if ((t & 63) == 0) { psum[w] = s; psq[w] = q; }
  __syncthreads();
  float S = psum[0] + psum[1] + psum[2] + psum[3];
  float Qs = psq[0] + psq[1] + psq[2] + psq[3];
  float u = S * (1.f / 1024.f);
  float var = Qs * (1.f / 1024.f) - u * u;
  float rstd = rsqrtf(var + 1e-12f);
  float4 gv = ((const float4*)g)[t];
  float4 bv = ((const float4*)be)[t];
  float4 o;
  o.x = gv.x * ((v.x - u) * rstd) + bv.x;
  o.y = gv.y * ((v.y - u) * rstd) + bv.y;
  o.z = gv.z * ((v.z - u) * rstd) + bv.z;
  o.w = gv.w * ((v.w - u) * rstd) + bv.w;
  ((float4*)(out + (size_t)tok * 1024))[t] = o;
}

extern "C" void kernel_launch(void* const* d_in, const int* in_sizes, int n_in,
                              void* d_out, int out_size, void* d_ws, size_t ws_size,
                              hipStream_t stream) {
  const float* hs   = (const float*)d_in[0];
  const float* mask = (const float*)d_in[1];
  const float* Wq   = (const float*)d_in[2];
  const float* bq   = (const float*)d_in[3];
  const float* Wk   = (const float*)d_in[4];
  const float* bk   = (const float*)d_in[5];
  const float* Wv   = (const float*)d_in[6];
  const float* bv   = (const float*)d_in[7];
  const float* Wo   = (const float*)d_in[8];
  const float* bo   = (const float*)d_in[9];
  const float* lnw  = (const float*)d_in[10];
  const float* lnb  = (const float*)d_in[11];

  float* out = (float*)d_out;
  float* probs = out + (size_t)4194304;  // B*S*D = 2*2048*1024

  char* ws = (char*)d_ws;
  const size_t MB = 1u << 20;
  unsigned short* hsb = (unsigned short*)(ws + 0 * MB);    // 8 MB
  unsigned short* TqW = (unsigned short*)(ws + 8 * MB);    // 2 MB each
  unsigned short* TkW = (unsigned short*)(ws + 10 * MB);
  unsigned short* TvW = (unsigned short*)(ws + 12 * MB);
  unsigned short* ToW = (unsigned short*)(ws + 14 * MB);
  unsigned short* Qb  = (unsigned short*)(ws + 16 * MB);   // 8 MB
  unsigned short* Kb  = (unsigned short*)(ws + 24 * MB);   // 8 MB
  unsigned short* VTb = (unsigned short*)(ws + 32 * MB);   // 8 MB
  unsigned short* ctxb = (unsigned short*)(ws + 40 * MB);  // 8 MB
  float* hbuf = (float*)(ws + 48 * MB);                    // 16 MB

  k_cast_hs<<<4096, 256, 0, stream>>>(hs, hsb, 1048576);
  k_transpose_cast<<<dim3(32, 32, 4), dim3(32, 8), 0, stream>>>(Wq, Wk, Wv, Wo, TqW, TkW, TvW, ToW);

  // Q = hs@Wq+bq, K = hs@Wk+bk  (rows=tokens M=4096, cols=D N=1024)
  k_gemm<0><<<dim3(8, 32), 256, 0, stream>>>(hsb, TqW, 1024, bq, nullptr, Qb);
  k_gemm<0><<<dim3(8, 32), 256, 0, stream>>>(hsb, TkW, 1024, bk, nullptr, Kb);
  // VT = (hs@Wv)^T = Wv^T @ hs^T  (rows=dims M=1024, cols=tokens N=4096)
  k_gemm<1><<<dim3(32, 8), 256, 0, stream>>>(TvW, hsb, 1024, bv, nullptr, VTb);

  k_attn<<<dim3(128, 16, 2), 256, 0, stream>>>(Qb, Kb, VTb, mask, probs, ctxb);

  // h = ctx@Wo + bo + hs
  k_gemm<2><<<dim3(8, 32), 256, 0, stream>>>(ctxb, ToW, 1024, bo, hs, hbuf);
  k_ln<<<4096, 256, 0, stream>>>(hbuf, lnw, lnb, out);
}